// Round 6
// baseline (246.679 us; speedup 1.0000x reference)
//
#include <hip/hip_runtime.h>

// ---------------------------------------------------------------------------
// SelfAttention: B=2,T=2048,D_IN=1024,E=64,H=16, causal, interleaved (E,H)
// R6: attn = one wave per (head,qtile), barrier-free, K/V direct-global frags,
//     P via private LDS. gemm_qkv = LDS double-buffer, 1 barrier/iter.
// Layouts: qh/kh [b][t][h*64+e] (Q pre-scaled), vh [b][h][e][t],
//          ot [b][t][h*64+e] with Wu k-rows permuted to match.
// ---------------------------------------------------------------------------

typedef __bf16 bf16x8 __attribute__((ext_vector_type(8)));
typedef float f32x4 __attribute__((ext_vector_type(4)));
typedef unsigned short u16;
typedef unsigned int u32;

#define AS1 __attribute__((address_space(1)))
#define AS3 __attribute__((address_space(3)))

__device__ __forceinline__ void gll16(const void* g, void* l) {
    __builtin_amdgcn_global_load_lds((const AS1 u32*)g, (AS3 u32*)l, 16, 0, 0);
}

__device__ __forceinline__ u16 f2bf(float f) {
    union { float f; u32 u; } v; v.f = f;
    u32 r = (v.u + 0x7FFFu + ((v.u >> 16) & 1u)) >> 16;   // RNE
    return (u16)r;
}

#define MM 4096           // B*T
#define SCALE_LOG2E 0.18033688011112042f   // log2(e)/sqrt(64)

// ---------------- kernel 1: cast inp -> bf16 ----------------
__global__ void cast_x(const float* __restrict__ in, u16* __restrict__ out, int n4) {
    int i = blockIdx.x * blockDim.x + threadIdx.x;
    if (i < n4) {
        float4 f = ((const float4*)in)[i];
        ushort4 o;
        o.x = f2bf(f.x); o.y = f2bf(f.y); o.z = f2bf(f.z); o.w = f2bf(f.w);
        ((ushort4*)out)[i] = o;
    }
}

// ---------------- kernel 2: W[k][n] fp32 -> Wt bf16 (permuted) ----------------
// Wq/Wk/Wv (n = e*16+h): row perm(n) = h*64+e.  Wu: k-col perm(k) = (k&15)*64+(k>>4).
__global__ void transpose_w(const float* __restrict__ Wq, const float* __restrict__ Wk,
                            const float* __restrict__ Wv, const float* __restrict__ Wu,
                            u16* __restrict__ wqt, u16* __restrict__ wkt,
                            u16* __restrict__ wvt, u16* __restrict__ wut) {
    int z = blockIdx.z;
    const float* src; u16* dst; int N;
    if (z == 0)      { src = Wq; dst = wqt; N = 1024; }
    else if (z == 1) { src = Wk; dst = wkt; N = 1024; }
    else if (z == 2) { src = Wv; dst = wvt; N = 1024; }
    else             { src = Wu; dst = wut; N = 64; if (blockIdx.y >= 2) return; }
    __shared__ float lds[32][33];
    int k0 = blockIdx.x * 32, n0 = blockIdx.y * 32;
    int tid = threadIdx.x;
    int c = tid & 31, r0 = tid >> 5;
#pragma unroll
    for (int p = 0; p < 4; ++p) {
        int r = r0 + p * 8;
        lds[r][c] = src[(k0 + r) * N + n0 + c];
    }
    __syncthreads();
#pragma unroll
    for (int p = 0; p < 4; ++p) {
        int n = n0 + r0 + p * 8;
        if (z < 3) {
            int rnew = ((n & 15) << 6) | (n >> 4);
            dst[rnew * 1024 + k0 + c] = f2bf(lds[c][n - n0]);
        } else {
            int k = k0 + c;
            int kp = ((k & 15) << 6) | (k >> 4);
            dst[n * 1024 + kp] = f2bf(lds[c][n - n0]);
        }
    }
}

// ---------------- kernel 3: fused QKV GEMM (LDS double-buffer) ----------------
// C[4096,3072] = Xb * W3^T. One barrier/iter: gll16 tile k+1 overlaps MFMA of k.
// Q/K: operand-swapped MFMA (D[n][m]) -> packed ushort4 stores.
__global__ __launch_bounds__(256, 3) void gemm_qkv(const u16* __restrict__ xb,
                                                   const u16* __restrict__ w3,
                                                   u16* __restrict__ qh, u16* __restrict__ kh,
                                                   u16* __restrict__ vh) {
    __shared__ u16 lA[2][128 * 32];
    __shared__ u16 lB[2][128 * 32];
    int tid = threadIdx.x;
    int n0 = blockIdx.x * 128, m0 = blockIdx.y * 128;
    int z = n0 >> 10;
    int lane = tid & 63, w = tid >> 6;
    int wr = w >> 1, wc = w & 1;
    int l15 = lane & 15, quad = lane >> 4;
    f32x4 acc[4][4] = {};
    int srow = tid >> 2, scol = (tid & 3) * 8;
    const u16* ga0 = xb + (m0 + srow) * 1024 + scol;
    const u16* ga1 = xb + (m0 + 64 + srow) * 1024 + scol;
    const u16* gb0 = w3 + (n0 + srow) * 1024 + scol;
    const u16* gb1 = w3 + (n0 + 64 + srow) * 1024 + scol;
    // prologue: tile 0 -> buf 0
    gll16(ga0, lA[0] + tid * 8);
    gll16(ga1, lA[0] + (256 + tid) * 8);
    gll16(gb0, lB[0] + tid * 8);
    gll16(gb1, lB[0] + (256 + tid) * 8);
#pragma unroll 2
    for (int kk = 0; kk < 32; ++kk) {
        int cur = kk & 1;
        __syncthreads();               // drains tile-kk loads; prev buf free
        if (kk < 31) {
            int kb1 = (kk + 1) * 32;
            gll16(ga0 + kb1, lA[cur ^ 1] + tid * 8);
            gll16(ga1 + kb1, lA[cur ^ 1] + (256 + tid) * 8);
            gll16(gb0 + kb1, lB[cur ^ 1] + tid * 8);
            gll16(gb1 + kb1, lB[cur ^ 1] + (256 + tid) * 8);
        }
        bf16x8 af[4], bfr[4];
#pragma unroll
        for (int i = 0; i < 4; ++i)
            af[i] = *(const bf16x8*)(lA[cur] + (wr * 64 + i * 16 + l15) * 32 + quad * 8);
#pragma unroll
        for (int j = 0; j < 4; ++j)
            bfr[j] = *(const bf16x8*)(lB[cur] + (wc * 64 + j * 16 + l15) * 32 + quad * 8);
        if (z < 2) {   // D[n][m]
#pragma unroll
            for (int i = 0; i < 4; ++i)
#pragma unroll
                for (int j = 0; j < 4; ++j)
                    acc[i][j] = __builtin_amdgcn_mfma_f32_16x16x32_bf16(bfr[j], af[i], acc[i][j], 0, 0, 0);
        } else {       // D[m][n]
#pragma unroll
            for (int i = 0; i < 4; ++i)
#pragma unroll
                for (int j = 0; j < 4; ++j)
                    acc[i][j] = __builtin_amdgcn_mfma_f32_16x16x32_bf16(af[i], bfr[j], acc[i][j], 0, 0, 0);
        }
    }
    int h = ((n0 & 1023) >> 6) + wc;
    int bb = m0 >> 11;
    if (z < 2) {
        u16* dst = (z == 0) ? qh : kh;
        float scale = (z == 0) ? SCALE_LOG2E : 1.f;
#pragma unroll
        for (int i = 0; i < 4; ++i) {
            int m = m0 + wr * 64 + i * 16 + l15;
#pragma unroll
            for (int j = 0; j < 4; ++j) {
                ushort4 o;
                o.x = f2bf(acc[i][j][0] * scale); o.y = f2bf(acc[i][j][1] * scale);
                o.z = f2bf(acc[i][j][2] * scale); o.w = f2bf(acc[i][j][3] * scale);
                *(ushort4*)(dst + m * 1024 + h * 64 + j * 16 + quad * 4) = o;
            }
        }
    } else {
#pragma unroll
        for (int i = 0; i < 4; ++i)
#pragma unroll
            for (int j = 0; j < 4; ++j) {
                int t4 = (m0 & 2047) + wr * 64 + i * 16 + quad * 4;
                ushort4 o;
                o.x = f2bf(acc[i][j][0]); o.y = f2bf(acc[i][j][1]);
                o.z = f2bf(acc[i][j][2]); o.w = f2bf(acc[i][j][3]);
                *(ushort4*)(vh + (((bb * 16 + h) * 64) + j * 16 + l15) * 2048 + t4) = o;
            }
    }
}

// ---------------- kernel 4: flash attention — one wave per (head,qtile) ----------------
// grid (32 heads, 32 qtiles) x 64 threads. Zero barriers. Wave owns 64 t-cols:
// S^T = K Q^T (4 t-subtiles), softmax per col via in-lane + quad butterfly,
// O^T += V^T P^T with P through private LDS. K/V frags loaded direct from
// global (L2-resident: all blocks of a head land on head%8's XCD).
__global__ __launch_bounds__(64, 2) void attn(const u16* __restrict__ qh, const u16* __restrict__ kh,
                                              const u16* __restrict__ vh, u16* __restrict__ ot) {
    __shared__ u16 sP[64 * 72];        // P^T as [t][s], stride 72 (9216 B)
    const int lane = threadIdx.x;
    const int quad = lane >> 4, l15 = lane & 15;
    const int head = blockIdx.x;       // head fastest -> fixed XCD per head
    const int qt = 31 - (int)blockIdx.y;   // heavy qtiles dispatch first
    const int b = head >> 4, h = head & 15;
    const u16* qb = qh + (b * 2048) * 1024 + h * 64;
    const u16* kb = kh + (b * 2048) * 1024 + h * 64;
    const u16* vb = vh + (head * 64) * 2048;
    // Q B-frags, persistent: aq[g][k2] for t = qt*64 + g*16 + l15
    bf16x8 aq[4][2];
#pragma unroll
    for (int g = 0; g < 4; ++g)
#pragma unroll
        for (int k2 = 0; k2 < 2; ++k2)
            aq[g][k2] = *(const bf16x8*)(qb + (qt * 64 + g * 16 + l15) * 1024 + k2 * 32 + quad * 8);
    f32x4 oacc[4][4] = {};             // [g][e4]
    float m_[4], l_[4];
#pragma unroll
    for (int g = 0; g < 4; ++g) { m_[g] = -3e38f; l_[g] = 0.f; }

    for (int jt = 0; jt <= qt; ++jt) {
        // K A-frags for this s-tile
        bf16x8 ak[4][2];
#pragma unroll
        for (int j4 = 0; j4 < 4; ++j4)
#pragma unroll
            for (int k2 = 0; k2 < 2; ++k2)
                ak[j4][k2] = *(const bf16x8*)(kb + (jt * 64 + j4 * 16 + l15) * 1024 + k2 * 32 + quad * 8);
        // S^T = K Q^T : sacc[g][j4], rows s=j4*16+quad*4+r, cols t=g*16+l15
        f32x4 sacc[4][4] = {};
#pragma unroll
        for (int g = 0; g < 4; ++g)
#pragma unroll
            for (int j4 = 0; j4 < 4; ++j4)
#pragma unroll
                for (int k2 = 0; k2 < 2; ++k2)
                    sacc[g][j4] = __builtin_amdgcn_mfma_f32_16x16x32_bf16(ak[j4][k2], aq[g][k2], sacc[g][j4], 0, 0, 0);
        if (jt == qt) {                // diagonal: mask s_local > t_local
#pragma unroll
            for (int g = 0; g < 4; ++g)
#pragma unroll
                for (int j4 = 0; j4 < 4; ++j4)
#pragma unroll
                    for (int r = 0; r < 4; ++r)
                        if (j4 * 16 + quad * 4 + r > g * 16 + l15) sacc[g][j4][r] = -1e30f;
        }
        // softmax per t-col: 16 in-lane + butterfly over quads (xor 16,32)
#pragma unroll
        for (int g = 0; g < 4; ++g) {
            float mx = -3e38f;
#pragma unroll
            for (int j4 = 0; j4 < 4; ++j4)
#pragma unroll
                for (int r = 0; r < 4; ++r) mx = fmaxf(mx, sacc[g][j4][r]);
            mx = fmaxf(mx, __shfl_xor(mx, 16));
            mx = fmaxf(mx, __shfl_xor(mx, 32));
            float mnew = fmaxf(m_[g], mx);
            float alpha = __builtin_amdgcn_exp2f(m_[g] - mnew);
            float rs = 0.f;
#pragma unroll
            for (int j4 = 0; j4 < 4; ++j4) {
                ushort4 o;
#pragma unroll
                for (int r = 0; r < 4; ++r) {
                    float pe = __builtin_amdgcn_exp2f(sacc[g][j4][r] - mnew);
                    rs += pe;
                    ((u16*)&o)[r] = f2bf(pe);
                }
                *(ushort4*)(sP + (g * 16 + l15) * 72 + j4 * 16 + quad * 4) = o;
            }
            rs += __shfl_xor(rs, 16);
            rs += __shfl_xor(rs, 32);
            l_[g] = l_[g] * alpha + rs;
            m_[g] = mnew;
#pragma unroll
            for (int e4 = 0; e4 < 4; ++e4) {
                oacc[g][e4][0] *= alpha; oacc[g][e4][1] *= alpha;
                oacc[g][e4][2] *= alpha; oacc[g][e4][3] *= alpha;
            }
        }
        // V^T A-frags (issued after P writes; latency overlaps bp reads)
        bf16x8 av[4][2];
#pragma unroll
        for (int e4 = 0; e4 < 4; ++e4)
#pragma unroll
            for (int k2 = 0; k2 < 2; ++k2)
                av[e4][k2] = *(const bf16x8*)(vb + (e4 * 16 + l15) * 2048 + jt * 64 + k2 * 32 + quad * 8);
        // O^T += V^T P^T per t-subtile
#pragma unroll
        for (int g = 0; g < 4; ++g) {
            bf16x8 bp[2];
            bp[0] = *(const bf16x8*)(sP + (g * 16 + l15) * 72 + quad * 8);
            bp[1] = *(const bf16x8*)(sP + (g * 16 + l15) * 72 + 32 + quad * 8);
#pragma unroll
            for (int e4 = 0; e4 < 4; ++e4)
#pragma unroll
                for (int k2 = 0; k2 < 2; ++k2)
                    oacc[g][e4] = __builtin_amdgcn_mfma_f32_16x16x32_bf16(av[e4][k2], bp[k2], oacc[g][e4], 0, 0, 0);
        }
    }
    // epilogue: O^T col t; e packed in regs -> ushort4 stores
#pragma unroll
    for (int g = 0; g < 4; ++g) {
        float inv = 1.f / l_[g];
        int t = qt * 64 + g * 16 + l15;
        u16* orow = ot + (b * 2048 + t) * 1024 + h * 64;
#pragma unroll
        for (int e4 = 0; e4 < 4; ++e4) {
            ushort4 o;
            o.x = f2bf(oacc[g][e4][0] * inv); o.y = f2bf(oacc[g][e4][1] * inv);
            o.z = f2bf(oacc[g][e4][2] * inv); o.w = f2bf(oacc[g][e4][3] * inv);
            *(ushort4*)(orow + e4 * 16 + quad * 4) = o;
        }
    }
}

// ---------------- kernel 5: out = ot[M,1024] @ Wu + bu ----------------
__global__ __launch_bounds__(256) void gemm_out(const u16* __restrict__ ot, const u16* __restrict__ wut,
                                                const float* __restrict__ bu, float* __restrict__ out) {
    __shared__ float red[4][1088];     // [w][n*17 + m]
    int tid = threadIdx.x, lane = tid & 63, w = tid >> 6;
    int quad = lane >> 4, l15 = lane & 15;
    int m0 = blockIdx.x * 16;
    f32x4 acc[4] = {};
    const u16* aptr = ot + (m0 + l15) * 1024 + w * 256 + quad * 8;
    const u16* bptr = wut + l15 * 1024 + w * 256 + quad * 8;
#pragma unroll
    for (int kk = 0; kk < 8; ++kk) {
        bf16x8 af = *(const bf16x8*)(aptr + kk * 32);
#pragma unroll
        for (int j = 0; j < 4; ++j) {
            bf16x8 bfr = *(const bf16x8*)(bptr + j * 16 * 1024 + kk * 32);
            acc[j] = __builtin_amdgcn_mfma_f32_16x16x32_bf16(af, bfr, acc[j], 0, 0, 0);
        }
    }
#pragma unroll
    for (int j = 0; j < 4; ++j)
#pragma unroll
        for (int r = 0; r < 4; ++r)
            red[w][(j * 16 + l15) * 17 + quad * 4 + r] = acc[j][r];
    __syncthreads();
    int n = tid & 63, mq = tid >> 6;
    float bias = bu[n];
#pragma unroll
    for (int i = 0; i < 4; ++i) {
        int m = mq * 4 + i;
        float s = red[0][n * 17 + m] + red[1][n * 17 + m] + red[2][n * 17 + m] + red[3][n * 17 + m];
        out[(m0 + m) * 64 + n] = s + bias;
    }
}

// ---------------- workspace layout (bytes) ----------------
#define OFF_XB   0u          /* 8 MB; ot aliases this (xb dead after gemm_qkv) */
#define OFF_WQT  8388608u    /* wqt/wkt/wvt contiguous = W3[3072][1024] */
#define OFF_WUT  14680064u   /* 128 KB */
#define OFF_QH   14811136u   /* 8 MB each */
#define OFF_KH   23199744u
#define OFF_VH   31588352u
#define OFF_OT   OFF_XB

extern "C" void kernel_launch(void* const* d_in, const int* in_sizes, int n_in,
                              void* d_out, int out_size, void* d_ws, size_t ws_size,
                              hipStream_t stream) {
    (void)in_sizes; (void)n_in; (void)out_size; (void)ws_size;
    const float* inp = (const float*)d_in[0];
    // d_in[1] = causal mask — implemented analytically
    const float* Wq = (const float*)d_in[2];
    const float* Wk = (const float*)d_in[3];
    const float* Wv = (const float*)d_in[4];
    const float* Wu = (const float*)d_in[5];
    const float* bu = (const float*)d_in[6];
    float* out = (float*)d_out;
    char* ws = (char*)d_ws;
    u16* xb  = (u16*)(ws + OFF_XB);
    u16* wqt = (u16*)(ws + OFF_WQT);
    u16* wkt = wqt + 1024 * 1024;
    u16* wvt = wqt + 2048 * 1024;
    u16* wut = (u16*)(ws + OFF_WUT);
    u16* qh  = (u16*)(ws + OFF_QH);
    u16* kh  = (u16*)(ws + OFF_KH);
    u16* vh  = (u16*)(ws + OFF_VH);
    u16* ot  = (u16*)(ws + OFF_OT);

    cast_x<<<4096, 256, 0, stream>>>(inp, xb, (MM * 1024) / 4);
    transpose_w<<<dim3(32, 32, 4), 256, 0, stream>>>(Wq, Wk, Wv, Wu, wqt, wkt, wvt, wut);
    gemm_qkv<<<dim3(24, 32), 256, 0, stream>>>(xb, wqt, qh, kh, vh);
    attn<<<dim3(32, 32), 64, 0, stream>>>(qh, kh, vh, ot);
    gemm_out<<<256, 256, 0, stream>>>(ot, wut, bu, out);
}